// Round 8
// baseline (436.452 us; speedup 1.0000x reference)
//
#include <hip/hip_runtime.h>
#include <hip/hip_bf16.h>

typedef unsigned short u16;
typedef short bf16x8 __attribute__((ext_vector_type(8)));
typedef float f32x4 __attribute__((ext_vector_type(4)));

#define GLDS16(gp, lp) __builtin_amdgcn_global_load_lds( \
    (const __attribute__((address_space(1))) void*)(gp), \
    (__attribute__((address_space(3))) void*)(lp), 16, 0, 0)

static __device__ __forceinline__ u16 f2b(float f) {
  unsigned u = __float_as_uint(f);
  u += 0x7fffu + ((u >> 16) & 1u);   // round-to-nearest-even
  return (u16)(u >> 16);
}
static __device__ __forceinline__ float b2f(u16 h) {
  return __uint_as_float(((unsigned)h) << 16);
}
static __device__ __forceinline__ f32x4 mfma16(bf16x8 a, bf16x8 b, f32x4 c) {
  return __builtin_amdgcn_mfma_f32_16x16x32_bf16(a, b, c, 0, 0, 0);
}
static __device__ __forceinline__ float fexp2(float x) {
  return __builtin_amdgcn_exp2f(x);   // v_exp_f32 computes 2^x natively
}

// RoPE table: [s][0..31]=cos, [s][32..63]=sin
__device__ __align__(16) float g_rope[2048][64];

__global__ void rope_fill()
{
  int i = blockIdx.x * 256 + threadIdx.x;   // 65536 = 2048*32
  int s = i >> 5, j = i & 31;
  float invf = __expf(-(float)j * 0.28782313662425575f);  // 10000^(-j/32)
  float ang = (float)s * invf;
  g_rope[s][j] = cosf(ang);
  g_rope[s][32 + j] = sinf(ang);
}

// ---------------- elementwise f32 -> bf16 ----------------
__global__ void conv_f32_bf16(const float* __restrict__ src, u16* __restrict__ dst, int n4)
{
  int stride = gridDim.x * blockDim.x;
  for (int i = blockIdx.x * blockDim.x + threadIdx.x; i < n4; i += stride) {
    float4 v = ((const float4*)src)[i];
    ushort4 o;
    o.x = f2b(v.x); o.y = f2b(v.y); o.z = f2b(v.z); o.w = f2b(v.w);
    ((ushort4*)dst)[i] = o;
  }
}

// ---------------- weight transpose + convert: src f32 [K][N] -> dst bf16 [N][K] (row offset) ----
__global__ void wtrans(const float* __restrict__ src, int K, int N,
                       u16* __restrict__ dst, int dld, int roff)
{
  __shared__ float tile[32][33];
  int n0 = blockIdx.x << 5, k0 = blockIdx.y << 5;
  int tx = threadIdx.x & 31, ty = threadIdx.x >> 5;   // ty 0..7
  #pragma unroll
  for (int p = 0; p < 4; ++p) {
    int kk = (p << 3) + ty;
    tile[kk][tx] = src[(size_t)(k0 + kk) * N + n0 + tx];
  }
  __syncthreads();
  #pragma unroll
  for (int p = 0; p < 4; ++p) {
    int nn = (p << 3) + ty;
    dst[(size_t)(roff + n0 + nn) * dld + k0 + tx] = f2b(tile[tx][nn]);
  }
}

// ---------------- GEMM v2: C = A * Bt^T, double-buffered staging, 1 barrier/K-step ----------
__global__ __launch_bounds__(256, 2)
void gemm_bt(const u16* __restrict__ A, const u16* __restrict__ Bt,
             void* __restrict__ C, int K, int lda, int ldb, int ldc, int c_f32)
{
  __shared__ u16 As[2][128 * 64];
  __shared__ u16 Bs[2][128 * 64];
  const int t = threadIdx.x;
  const int lane = t & 63;
  const int m0 = blockIdx.y << 7, n0 = blockIdx.x << 7;
  const int w = t >> 6;
  const int wm = (w >> 1) << 6;   // 0 or 64
  const int wn = (w & 1) << 6;
  const int r15 = lane & 15, hi = lane >> 4;

  f32x4 acc[4][4];
  #pragma unroll
  for (int i = 0; i < 4; ++i)
    #pragma unroll
    for (int j = 0; j < 4; ++j)
      acc[i][j] = (f32x4){0.f, 0.f, 0.f, 0.f};

  auto STAGE = [&](int buf, int kt) {
    #pragma unroll
    for (int p = 0; p < 4; ++p) {
      int g = (p << 8) + t;
      int row = g >> 3;
      int sl = (g & 7) ^ (row & 7);
      const u16* ga = A + (size_t)(m0 + row) * lda + kt + (sl << 3);
      GLDS16(ga, (char*)As[buf] + g * 16);
      const u16* gb = Bt + (size_t)(n0 + row) * ldb + kt + (sl << 3);
      GLDS16(gb, (char*)Bs[buf] + g * 16);
    }
  };

  const int nk = K >> 6;
  STAGE(0, 0);
  __syncthreads();

  for (int ki = 0; ki < nk; ++ki) {
    int kn = (ki + 1 < nk) ? ki + 1 : ki;         // clamp: last iter re-stages (idle buffer)
    STAGE((ki + 1) & 1, kn << 6);                  // issue next-tile loads FIRST
    const char* Ab = (const char*)As[ki & 1];
    const char* Bb = (const char*)Bs[ki & 1];
    #pragma unroll
    for (int kk = 0; kk < 2; ++kk) {
      int ks = (kk << 2) + hi;
      bf16x8 af[4], bfr[4];
      #pragma unroll
      for (int mi = 0; mi < 4; ++mi) {
        int row = wm + (mi << 4) + r15;
        af[mi] = *(const bf16x8*)(Ab + row * 128 + ((ks ^ (row & 7)) << 4));
      }
      #pragma unroll
      for (int ni = 0; ni < 4; ++ni) {
        int row = wn + (ni << 4) + r15;
        bfr[ni] = *(const bf16x8*)(Bb + row * 128 + ((ks ^ (row & 7)) << 4));
      }
      #pragma unroll
      for (int mi = 0; mi < 4; ++mi)
        #pragma unroll
        for (int ni = 0; ni < 4; ++ni)
          acc[mi][ni] = mfma16(af[mi], bfr[ni], acc[mi][ni]);
    }
    __syncthreads();   // drains own next-tile loads + rendezvous => buffer ready for ki+1
  }

  if (c_f32) {
    float* Cf = (float*)C;
    #pragma unroll
    for (int mi = 0; mi < 4; ++mi)
      #pragma unroll
      for (int ni = 0; ni < 4; ++ni) {
        int row = m0 + wm + (mi << 4) + (hi << 2);
        int col = n0 + wn + (ni << 4) + r15;
        #pragma unroll
        for (int r = 0; r < 4; ++r)
          Cf[(size_t)(row + r) * ldc + col] = acc[mi][ni][r];
      }
  } else {
    u16* Cb = (u16*)C;
    #pragma unroll
    for (int mi = 0; mi < 4; ++mi)
      #pragma unroll
      for (int ni = 0; ni < 4; ++ni) {
        int row = m0 + wm + (mi << 4) + (hi << 2);
        int col = n0 + wn + (ni << 4) + r15;
        #pragma unroll
        for (int r = 0; r < 4; ++r)
          Cb[(size_t)(row + r) * ldc + col] = f2b(acc[mi][ni][r]);
      }
  }
}

// ---------------- pack Q: concat(nope, rope(pe)) * scale -> Q[b][h][s][128] ----------------
__global__ void pack_q(const u16* __restrict__ qout, u16* __restrict__ Qb)
{
  int rid = (blockIdx.x << 2) + (threadIdx.x >> 6);
  int lane = threadIdx.x & 63;
  int s = rid & 2047, h = (rid >> 11) & 15;
  int b = rid >> 15;
  const u16* src = qout + (size_t)((b << 11) + s) * 2048;
  const float scale = 0.12751743f;   // 128^-0.5 * log2(e)
  float vn = b2f(src[(h << 6) + lane]) * scale;
  int j = lane & 31;
  float t1 = b2f(src[1024 + (h << 6) + j]);
  float t2 = b2f(src[1024 + (h << 6) + 32 + j]);
  float c = g_rope[s][j], sn = g_rope[s][32 + j];
  float vp = (lane < 32) ? (t1 * c - t2 * sn) : (t1 * sn + t2 * c);
  vp *= scale;
  u16* dst = Qb + (size_t)rid * 128;
  dst[lane] = f2b(vn);
  dst[64 + lane] = f2b(vp);
}

// ---------------- pack K: nope from kvout, rope(pe) from lat1 -> K[b][h][s][128] ----------------
__global__ void pack_k(const u16* __restrict__ kvout, const u16* __restrict__ lat1,
                       u16* __restrict__ Kb)
{
  int rid = (blockIdx.x << 2) + (threadIdx.x >> 6);
  int lane = threadIdx.x & 63;
  int s = rid & 2047, h = (rid >> 11) & 15;
  int b = rid >> 15;
  size_t row = (size_t)((b << 11) + s);
  float vn = b2f(kvout[row * 3072 + (h << 6) + lane]);
  int j = lane & 31;
  float t1 = b2f(lat1[row * 2560 + 1536 + (h << 6) + j]);
  float t2 = b2f(lat1[row * 2560 + 1536 + (h << 6) + 32 + j]);
  float c = g_rope[s][j], sn = g_rope[s][32 + j];
  float vp = (lane < 32) ? (t1 * c - t2 * sn) : (t1 * sn + t2 * c);
  u16* dst = Kb + (size_t)rid * 128;
  dst[lane] = f2b(vn);
  dst[64 + lane] = f2b(vp);
}

// ---------------- pack V transposed: Vt[b][h][d=128][s=2048] ----------------
__global__ void pack_vt(const u16* __restrict__ kvout, u16* __restrict__ Vt)
{
  __shared__ u16 tile[32][33];
  int bi = blockIdx.x;
  int dt = bi & 3, st = (bi >> 2) & 63, h = (bi >> 8) & 15, b = bi >> 12;
  int tx = threadIdx.x & 31, ty = threadIdx.x >> 5;
  #pragma unroll
  for (int p = 0; p < 4; ++p) {
    int s = (st << 5) + (p << 3) + ty;
    tile[(p << 3) + ty][tx] =
        kvout[(size_t)((b << 11) + s) * 3072 + 1024 + (h << 7) + (dt << 5) + tx];
  }
  __syncthreads();
  #pragma unroll
  for (int p = 0; p < 4; ++p) {
    int d = (dt << 5) + (p << 3) + ty;
    Vt[(size_t)(((b << 4) + h) * 128 + d) * 2048 + (st << 5) + tx] = tile[tx][(p << 3) + ty];
  }
}

// ---------------- causal flash attention v4: swapped-QK^T + issue-early staging ----------------
// K double-buffered (staged 1 tile ahead, full-iteration latency window); V single-buffered
// (issued at top of iter, drained at mid-iter barrier after QK^T+softmax ~400cyc).
// All staging issued by all waves; barriers unconditional; compute wave-uniform predicated.
__global__ __launch_bounds__(512, 4)
void attn_fwd(const u16* __restrict__ Qb, const u16* __restrict__ Kb,
              const u16* __restrict__ Vt, u16* __restrict__ AO)
{
  __shared__ __align__(16) u16 Kl[2][64 * 128]; // 2 x 16KB, 16 chunks/row, XOR(row&15)
  __shared__ __align__(16) u16 Vl[128 * 64];    // 16KB, 8 chunks/row, XOR(row&7)
  __shared__ __align__(16) u16 Pl[8][16 * 64];  // per-wave P^T: [q=16][kv=64], pitch 128B

  const int S = 2048;
  int g = (int)(blockIdx.x >> 5);
  int qtg = (g < 8) ? (15 - g) : (g - 8);      // co-resident pair (bid,bid+256) sums constant
  int bh = blockIdx.x & 31;
  int b = bh >> 4, h = bh & 15;
  int t = threadIdx.x, lane = t & 63, w = t >> 6;
  int q0 = qtg << 7;
  int qw = q0 + (w << 4);
  int r15 = lane & 15, hi = lane >> 4;

  const u16* Qp = Qb + (size_t)bh * S * 128;
  const u16* Kp = Kb + (size_t)bh * S * 128;
  const u16* Vp = Vt + (size_t)bh * 128 * S;

  bf16x8 qf[4];
  #pragma unroll
  for (int kk = 0; kk < 4; ++kk)
    qf[kk] = *(const bf16x8*)(Qp + (size_t)(qw + r15) * 128 + kk * 32 + hi * 8);

  f32x4 o[8];
  #pragma unroll
  for (int i = 0; i < 8; ++i) o[i] = (f32x4){0.f, 0.f, 0.f, 0.f};
  float mrun = -1e30f, lrun = 0.f;   // per-lane, q = qw + r15 (log2 domain)

  int qme = qw + r15;
  u16* pw = Pl[w];

  auto STAGE_K = [&](int buf, int kt) {
    #pragma unroll
    for (int p = 0; p < 2; ++p) {
      int gg = t + (p << 9);
      int rk = gg >> 4, ck = gg & 15, sk = ck ^ (rk & 15);
      const u16* ga = Kp + (size_t)((kt << 6) + rk) * 128 + (sk << 3);
      GLDS16(ga, (char*)Kl[buf] + gg * 16);
    }
  };
  auto STAGE_V = [&](int kt) {
    #pragma unroll
    for (int p = 0; p < 2; ++p) {
      int gg = t + (p << 9);
      int rv = gg >> 3, cv = gg & 7, sv = cv ^ (rv & 7);
      const u16* gv = Vp + (size_t)rv * S + (kt << 6) + (sv << 3);
      GLDS16(gv, (char*)Vl + gg * 16);
    }
  };

  const int ntiles = (qtg << 1) + 2;
  STAGE_K(0, 0);
  __syncthreads();

  for (int kt = 0; kt < ntiles; ++kt) {
    int kv0 = kt << 6;
    int ktn = (kt + 1 < ntiles) ? kt + 1 : kt;   // clamp: last iter re-stages idle buffer
    STAGE_V(kt);                                  // consumed after mid-iter barrier
    STAGE_K((kt + 1) & 1, ktn);                   // consumed next iteration

    bool part = (kv0 <= qw + 15);
    bf16x8 pf[2];
    if (part) {
      // ---- QK^T swapped from pre-staged K: sc[nt][r] = S[kv=kv0+nt*16+hi*4+r][q=qme] ----
      const char* Kcur = (const char*)Kl[kt & 1];
      f32x4 sc[4];
      __builtin_amdgcn_s_setprio(1);
      #pragma unroll
      for (int nt = 0; nt < 4; ++nt) {
        f32x4 a = (f32x4){0.f, 0.f, 0.f, 0.f};
        int row = (nt << 4) + r15;
        #pragma unroll
        for (int kk = 0; kk < 4; ++kk) {
          int ch = (kk << 2) + hi;
          bf16x8 kf = *(const bf16x8*)(Kcur + row * 256 + ((ch ^ (row & 15)) << 4));
          a = mfma16(kf, qf[kk], a);
        }
        sc[nt] = a;
      }
      __builtin_amdgcn_s_setprio(0);

      // ---- mask (diagonal tiles only) ----
      if (kv0 + 63 > qw) {
        #pragma unroll
        for (int nt = 0; nt < 4; ++nt) {
          int kvb = kv0 + (nt << 4) + (hi << 2);
          #pragma unroll
          for (int r = 0; r < 4; ++r)
            sc[nt][r] = (kvb + r <= qme) ? sc[nt][r] : -1e30f;
        }
      }

      // ---- online softmax: in-lane over 16 values + 2 hops ----
      f32x4 mx = sc[0];
      #pragma unroll
      for (int nt = 1; nt < 4; ++nt) {
        mx[0] = fmaxf(mx[0], sc[nt][0]); mx[1] = fmaxf(mx[1], sc[nt][1]);
        mx[2] = fmaxf(mx[2], sc[nt][2]); mx[3] = fmaxf(mx[3], sc[nt][3]);
      }
      float mt = fmaxf(fmaxf(mx[0], mx[1]), fmaxf(mx[2], mx[3]));
      mt = fmaxf(mt, __shfl_xor(mt, 16, 64));
      mt = fmaxf(mt, __shfl_xor(mt, 32, 64));
      float mn = fmaxf(mrun, mt);
      float cr = fexp2(mrun - mn);
      float ps = 0.f;
      #pragma unroll
      for (int nt = 0; nt < 4; ++nt) {
        #pragma unroll
        for (int r = 0; r < 4; ++r) {
          float pv = fexp2(sc[nt][r] - mn);
          sc[nt][r] = pv;
          ps += pv;
        }
      }
      ps += __shfl_xor(ps, 16, 64);
      ps += __shfl_xor(ps, 32, 64);
      lrun = lrun * cr + ps;
      mrun = mn;

      // ---- rescale O^T ----
      #pragma unroll
      for (int dt = 0; dt < 8; ++dt) {
        f32x4 t4 = o[dt];
        t4[0] *= cr; t4[1] *= cr; t4[2] *= cr; t4[3] *= cr;
        o[dt] = t4;
      }

      // ---- P^T -> per-wave LDS, then reread as B-fragment (per-wave private) ----
      #pragma unroll
      for (int nt = 0; nt < 4; ++nt) {
        ushort4 pk;
        pk.x = f2b(sc[nt][0]); pk.y = f2b(sc[nt][1]);
        pk.z = f2b(sc[nt][2]); pk.w = f2b(sc[nt][3]);
        int chunk = ((nt << 1) + (hi >> 1)) ^ (r15 & 7);
        *(ushort4*)((char*)pw + r15 * 128 + (chunk << 4) + ((hi & 1) << 3)) = pk;
      }
      #pragma unroll
      for (int m = 0; m < 2; ++m) {
        int chunk = ((m << 2) + hi) ^ (r15 & 7);
        pf[m] = *(const bf16x8*)((const char*)pw + r15 * 128 + (chunk << 4));
      }
    }

    __syncthreads();   // per-wave vmcnt(0) drain + rendezvous => Vl (and K next) ready

    if (part) {
      // ---- PV: o^T += V^T * P^T ----
      __builtin_amdgcn_s_setprio(1);
      #pragma unroll
      for (int dt = 0; dt < 8; ++dt) {
        int vrow = (dt << 4) + r15;
        #pragma unroll
        for (int m = 0; m < 2; ++m) {
          int chv = (m << 2) + hi;
          bf16x8 vf = *(const bf16x8*)((const char*)Vl + vrow * 128 + ((chv ^ (vrow & 7)) << 4));
          o[dt] = mfma16(vf, pf[m], o[dt]);
        }
      }
      __builtin_amdgcn_s_setprio(0);
    }

    __syncthreads();   // all PV reads of Vl done before next iter overwrites it
  }

  // epilogue: normalize, pack d-contiguous ushort4, store AO[b*S+q][h*128+d]
  float inv = 1.0f / lrun;
  size_t rowb = (size_t)(b * 2048 + qw + r15) * 2048 + h * 128 + (hi << 2);
  #pragma unroll
  for (int dt = 0; dt < 8; ++dt) {
    ushort4 ov;
    ov.x = f2b(o[dt][0] * inv); ov.y = f2b(o[dt][1] * inv);
    ov.z = f2b(o[dt][2] * inv); ov.w = f2b(o[dt][3] * inv);
    *(ushort4*)(AO + rowb + (dt << 4)) = ov;
  }
}

// ---------------- host ----------------
extern "C" void kernel_launch(void* const* d_in, const int* in_sizes, int n_in,
                              void* d_out, int out_size, void* d_ws, size_t ws_size,
                              hipStream_t stream)
{
  const float* x        = (const float*)d_in[0];
  const float* Wq_down  = (const float*)d_in[1];
  const float* Wq_up    = (const float*)d_in[2];
  const float* Wq_rope  = (const float*)d_in[3];
  const float* Wkv_down = (const float*)d_in[4];
  const float* Wk_up    = (const float*)d_in[5];
  const float* Wk_rope  = (const float*)d_in[6];
  const float* Wv_up    = (const float*)d_in[7];
  const float* Wo       = (const float*)d_in[8];

  char* ws = (char*)d_ws;
  u16* xb    = (u16*)(ws + 0);          // 16 MB; reused as AO after GEMM1
  u16* W1t   = (u16*)(ws + 16777216);   // [2560][2048]
  u16* W2t   = (u16*)(ws + 27262976);   // [2048][1024]
  u16* W3t   = (u16*)(ws + 31457280);   // [3072][512]
  u16* Wot   = (u16*)(ws + 34603008);   // [2048][2048]
  u16* lat1  = (u16*)(ws + 42991616);   // [4096][2560]  q_lat|kv_lat|k_pe_raw
  u16* qout  = (u16*)(ws + 63963136);   // [4096][2048]  q_nope|q_pe_raw
  u16* kvout = (u16*)(ws + 80740352);   // [4096][3072]  k_nope|v
  u16* Qb    = (u16*)(ws + 105906176);  // [32][2048][128]
  u16* Kb    = (u16*)(ws + 122683392);
  u16* Vtb   = (u16*)(ws + 139460608);  // [32][128][2048]
  u16* AO    = xb;
  if (ws_size < 156237824u) return;     // visible failure instead of OOB

  rope_fill<<<256, 256, 0, stream>>>();
  conv_f32_bf16<<<2048, 256, 0, stream>>>(x, xb, 2097152);

  wtrans<<<dim3(32, 64), 256, 0, stream>>>(Wq_down,  2048, 1024, W1t, 2048, 0);
  wtrans<<<dim3(16, 64), 256, 0, stream>>>(Wkv_down, 2048,  512, W1t, 2048, 1024);
  wtrans<<<dim3(32, 64), 256, 0, stream>>>(Wk_rope,  2048, 1024, W1t, 2048, 1536);
  wtrans<<<dim3(32, 32), 256, 0, stream>>>(Wq_up,    1024, 1024, W2t, 1024, 0);
  wtrans<<<dim3(32, 32), 256, 0, stream>>>(Wq_rope,  1024, 1024, W2t, 1024, 1024);
  wtrans<<<dim3(32, 16), 256, 0, stream>>>(Wk_up,     512, 1024, W3t,  512, 0);
  wtrans<<<dim3(64, 16), 256, 0, stream>>>(Wv_up,     512, 2048, W3t,  512, 1024);
  wtrans<<<dim3(64, 64), 256, 0, stream>>>(Wo,       2048, 2048, Wot, 2048, 0);

  // lat1 = xb @ [Wq_down|Wkv_down|Wk_rope]
  gemm_bt<<<dim3(20, 32), 256, 0, stream>>>(xb, W1t, lat1, 2048, 2048, 2048, 2560, 0);
  // qout = q_lat @ [Wq_up|Wq_rope]
  gemm_bt<<<dim3(16, 32), 256, 0, stream>>>(lat1, W2t, qout, 1024, 2560, 1024, 2048, 0);
  // kvout = kv_lat @ [Wk_up|Wv_up]
  gemm_bt<<<dim3(24, 32), 256, 0, stream>>>(lat1 + 1024, W3t, kvout, 512, 2560, 512, 3072, 0);

  pack_q<<<16384, 256, 0, stream>>>(qout, Qb);
  pack_k<<<16384, 256, 0, stream>>>(kvout, lat1, Kb);
  pack_vt<<<8192, 256, 0, stream>>>(kvout, Vtb);

  attn_fwd<<<512, 512, 0, stream>>>(Qb, Kb, Vtb, AO);

  // out = AO @ Wo  (f32 out)
  gemm_bt<<<dim3(16, 32), 256, 0, stream>>>(AO, Wot, d_out, 2048, 2048, 2048, 2048, 1);

  (void)in_sizes; (void)n_in; (void)out_size;
}

// Round 9
// 366.188 us; speedup vs baseline: 1.1919x; 1.1919x over previous
//
#include <hip/hip_runtime.h>
#include <hip/hip_bf16.h>

typedef unsigned short u16;
typedef short bf16x8 __attribute__((ext_vector_type(8)));
typedef float f32x4 __attribute__((ext_vector_type(4)));

#define GLDS16(gp, lp) __builtin_amdgcn_global_load_lds( \
    (const __attribute__((address_space(1))) void*)(gp), \
    (__attribute__((address_space(3))) void*)(lp), 16, 0, 0)

static __device__ __forceinline__ u16 f2b(float f) {
  unsigned u = __float_as_uint(f);
  u += 0x7fffu + ((u >> 16) & 1u);   // round-to-nearest-even
  return (u16)(u >> 16);
}
static __device__ __forceinline__ float b2f(u16 h) {
  return __uint_as_float(((unsigned)h) << 16);
}
static __device__ __forceinline__ f32x4 mfma16(bf16x8 a, bf16x8 b, f32x4 c) {
  return __builtin_amdgcn_mfma_f32_16x16x32_bf16(a, b, c, 0, 0, 0);
}
static __device__ __forceinline__ float fexp2(float x) {
  return __builtin_amdgcn_exp2f(x);   // v_exp_f32 computes 2^x natively
}

// RoPE table: [s][0..31]=cos, [s][32..63]=sin
__device__ __align__(16) float g_rope[2048][64];

__global__ void rope_fill()
{
  int i = blockIdx.x * 256 + threadIdx.x;   // 65536 = 2048*32
  int s = i >> 5, j = i & 31;
  float invf = __expf(-(float)j * 0.28782313662425575f);  // 10000^(-j/32)
  float ang = (float)s * invf;
  g_rope[s][j] = cosf(ang);
  g_rope[s][32 + j] = sinf(ang);
}

// ---------------- elementwise f32 -> bf16 ----------------
__global__ void conv_f32_bf16(const float* __restrict__ src, u16* __restrict__ dst, int n4)
{
  int stride = gridDim.x * blockDim.x;
  for (int i = blockIdx.x * blockDim.x + threadIdx.x; i < n4; i += stride) {
    float4 v = ((const float4*)src)[i];
    ushort4 o;
    o.x = f2b(v.x); o.y = f2b(v.y); o.z = f2b(v.z); o.w = f2b(v.w);
    ((ushort4*)dst)[i] = o;
  }
}

// ---------------- weight transpose + convert: src f32 [K][N] -> dst bf16 [N][K] (row offset) ----
__global__ void wtrans(const float* __restrict__ src, int K, int N,
                       u16* __restrict__ dst, int dld, int roff)
{
  __shared__ float tile[32][33];
  int n0 = blockIdx.x << 5, k0 = blockIdx.y << 5;
  int tx = threadIdx.x & 31, ty = threadIdx.x >> 5;   // ty 0..7
  #pragma unroll
  for (int p = 0; p < 4; ++p) {
    int kk = (p << 3) + ty;
    tile[kk][tx] = src[(size_t)(k0 + kk) * N + n0 + tx];
  }
  __syncthreads();
  #pragma unroll
  for (int p = 0; p < 4; ++p) {
    int nn = (p << 3) + ty;
    dst[(size_t)(roff + n0 + nn) * dld + k0 + tx] = f2b(tile[tx][nn]);
  }
}

// ---------------- GEMM: C[M][N] = A[M][K] * Bt[N][K]^T, single-buffer (R7 structure) --------
// mode 0: bf16 C    mode 1: f32 C
// mode 2 (GEMM1): n0<1536 -> bf16 C (lat1); n0>=1536 -> rope(k_pe) -> aux1=Kb[...][64..127]
// mode 3 (GEMM2): n0<1024 -> Qb nope*scale; else rope(q_pe)*scale -> aux1=Qb[...][64..127]
// mode 4 (GEMM3): n0<1024 -> aux1=Kb[...][0..63]; else V transposed -> aux2=Vt[bh][d][s]
__global__ __launch_bounds__(256, 2)
void gemm_bt(const u16* __restrict__ A, const u16* __restrict__ Bt,
             void* __restrict__ C, int K, int lda, int ldb, int ldc,
             int mode, u16* __restrict__ aux1, u16* __restrict__ aux2)
{
  __shared__ u16 As[128 * 64];
  __shared__ u16 Bs[128 * 64];
  const int t = threadIdx.x;
  const int lane = t & 63;
  const int m0 = blockIdx.y << 7, n0 = blockIdx.x << 7;
  const int w = t >> 6;
  const int wm = (w >> 1) << 6;   // 0 or 64
  const int wn = (w & 1) << 6;
  const int r15 = lane & 15, hi = lane >> 4;

  f32x4 acc[4][4];
  #pragma unroll
  for (int i = 0; i < 4; ++i)
    #pragma unroll
    for (int j = 0; j < 4; ++j)
      acc[i][j] = (f32x4){0.f, 0.f, 0.f, 0.f};

  for (int kt = 0; kt < K; kt += 64) {
    __syncthreads();
    #pragma unroll
    for (int p = 0; p < 4; ++p) {
      int g = (p << 8) + t;
      int row = g >> 3;
      int sl = (g & 7) ^ (row & 7);
      const u16* ga = A + (size_t)(m0 + row) * lda + kt + (sl << 3);
      GLDS16(ga, (char*)As + g * 16);
      const u16* gb = Bt + (size_t)(n0 + row) * ldb + kt + (sl << 3);
      GLDS16(gb, (char*)Bs + g * 16);
    }
    __syncthreads();
    #pragma unroll
    for (int kk = 0; kk < 2; ++kk) {
      int ks = (kk << 2) + hi;
      bf16x8 af[4], bfr[4];
      #pragma unroll
      for (int mi = 0; mi < 4; ++mi) {
        int row = wm + (mi << 4) + r15;
        af[mi] = *(const bf16x8*)((const char*)As + row * 128 + ((ks ^ (row & 7)) << 4));
      }
      #pragma unroll
      for (int ni = 0; ni < 4; ++ni) {
        int row = wn + (ni << 4) + r15;
        bfr[ni] = *(const bf16x8*)((const char*)Bs + row * 128 + ((ks ^ (row & 7)) << 4));
      }
      #pragma unroll
      for (int mi = 0; mi < 4; ++mi)
        #pragma unroll
        for (int ni = 0; ni < 4; ++ni)
          acc[mi][ni] = mfma16(af[mi], bfr[ni], acc[mi][ni]);
    }
  }

  const int row0 = m0 + wm + (hi << 2);

  if (mode == 1) {
    float* Cf = (float*)C;
    #pragma unroll
    for (int mi = 0; mi < 4; ++mi)
      #pragma unroll
      for (int ni = 0; ni < 4; ++ni) {
        int row = row0 + (mi << 4);
        int col = n0 + wn + (ni << 4) + r15;
        #pragma unroll
        for (int r = 0; r < 4; ++r)
          Cf[(size_t)(row + r) * ldc + col] = acc[mi][ni][r];
      }
  } else if (mode == 0 || (mode == 2 && n0 < 1536)) {
    u16* Cb = (u16*)C;
    #pragma unroll
    for (int mi = 0; mi < 4; ++mi)
      #pragma unroll
      for (int ni = 0; ni < 4; ++ni) {
        int row = row0 + (mi << 4);
        int col = n0 + wn + (ni << 4) + r15;
        #pragma unroll
        for (int r = 0; r < 4; ++r)
          Cb[(size_t)(row + r) * ldc + col] = f2b(acc[mi][ni][r]);
      }
  } else if (mode == 3 && n0 < 1024) {
    // Qb nope: d = col&63, h = col>>6, scaled
    const float qs = 0.12751743f;   // 128^-0.5 * log2(e)
    #pragma unroll
    for (int mi = 0; mi < 4; ++mi)
      #pragma unroll
      for (int ni = 0; ni < 4; ++ni) {
        int col = n0 + wn + (ni << 4) + r15;
        int hh = col >> 6, d = col & 63;
        #pragma unroll
        for (int r = 0; r < 4; ++r) {
          int row = row0 + (mi << 4) + r;
          int b_ = row >> 11, s = row & 2047;
          aux1[((size_t)(((b_ << 4) + hh) << 11) + s) * 128 + d] = f2b(acc[mi][ni][r] * qs);
        }
      }
  } else if (mode == 4 && n0 < 1024) {
    // Kb nope: d = col&63, h = col>>6, unscaled
    #pragma unroll
    for (int mi = 0; mi < 4; ++mi)
      #pragma unroll
      for (int ni = 0; ni < 4; ++ni) {
        int col = n0 + wn + (ni << 4) + r15;
        int hh = col >> 6, d = col & 63;
        #pragma unroll
        for (int r = 0; r < 4; ++r) {
          int row = row0 + (mi << 4) + r;
          int b_ = row >> 11, s = row & 2047;
          aux1[((size_t)(((b_ << 4) + hh) << 11) + s) * 128 + d] = f2b(acc[mi][ni][r]);
        }
      }
  } else if (mode == 4) {
    // V transposed: Vt[bh][d][s], 4 consecutive s per thread -> ushort4
    #pragma unroll
    for (int mi = 0; mi < 4; ++mi)
      #pragma unroll
      for (int ni = 0; ni < 4; ++ni) {
        int rel = (n0 - 1024) + wn + (ni << 4) + r15;
        int hh = rel >> 7, d = rel & 127;
        int row_s0 = row0 + (mi << 4);
        int b_ = row_s0 >> 11, s0 = row_s0 & 2047;
        ushort4 ov;
        ov.x = f2b(acc[mi][ni][0]); ov.y = f2b(acc[mi][ni][1]);
        ov.z = f2b(acc[mi][ni][2]); ov.w = f2b(acc[mi][ni][3]);
        *(ushort4*)(aux2 + ((size_t)(((b_ << 4) + hh) << 7) + d) * 2048 + s0) = ov;
      }
  } else {
    // rope-pair epilogue: mode 2 (k_pe -> Kb, unscaled) or mode 3 (q_pe -> Qb, scaled)
    const int boff = (mode == 2) ? 1536 : 1024;
    const float qs = (mode == 3) ? 0.12751743f : 1.0f;
    #pragma unroll
    for (int mi = 0; mi < 4; ++mi)
      #pragma unroll
      for (int ni = 0; ni < 2; ++ni) {          // lo half; hi partner = acc[mi][ni|2]
        int rel = (n0 - boff) + wn + (ni << 4) + r15;
        int hh = rel >> 6, j = rel & 31;
        #pragma unroll
        for (int r = 0; r < 4; ++r) {
          int row = row0 + (mi << 4) + r;
          int b_ = row >> 11, s = row & 2047;
          float t1 = acc[mi][ni][r] * qs;
          float t2 = acc[mi][ni | 2][r] * qs;
          float c = g_rope[s][j], sn = g_rope[s][32 + j];
          size_t base = ((size_t)(((b_ << 4) + hh) << 11) + s) * 128;
          aux1[base + 64 + j] = f2b(t1 * c - t2 * sn);
          aux1[base + 96 + j] = f2b(t1 * sn + t2 * c);
        }
      }
  }
}

// ---------------- causal flash attention v4: swapped-QK^T + issue-early staging ----------------
__global__ __launch_bounds__(512, 4)
void attn_fwd(const u16* __restrict__ Qb, const u16* __restrict__ Kb,
              const u16* __restrict__ Vt, u16* __restrict__ AO)
{
  __shared__ __align__(16) u16 Kl[2][64 * 128]; // 2 x 16KB, 16 chunks/row, XOR(row&15)
  __shared__ __align__(16) u16 Vl[128 * 64];    // 16KB, 8 chunks/row, XOR(row&7)
  __shared__ __align__(16) u16 Pl[8][16 * 64];  // per-wave P^T: [q=16][kv=64], pitch 128B

  const int S = 2048;
  int g = (int)(blockIdx.x >> 5);
  int qtg = (g < 8) ? (15 - g) : (g - 8);      // co-resident pair (bid,bid+256) sums constant
  int bh = blockIdx.x & 31;
  int b = bh >> 4, h = bh & 15;
  int t = threadIdx.x, lane = t & 63, w = t >> 6;
  int q0 = qtg << 7;
  int qw = q0 + (w << 4);
  int r15 = lane & 15, hi = lane >> 4;

  const u16* Qp = Qb + (size_t)bh * S * 128;
  const u16* Kp = Kb + (size_t)bh * S * 128;
  const u16* Vp = Vt + (size_t)bh * 128 * S;

  bf16x8 qf[4];
  #pragma unroll
  for (int kk = 0; kk < 4; ++kk)
    qf[kk] = *(const bf16x8*)(Qp + (size_t)(qw + r15) * 128 + kk * 32 + hi * 8);

  f32x4 o[8];
  #pragma unroll
  for (int i = 0; i < 8; ++i) o[i] = (f32x4){0.f, 0.f, 0.f, 0.f};
  float mrun = -1e30f, lrun = 0.f;   // per-lane, q = qw + r15 (log2 domain)

  int qme = qw + r15;
  u16* pw = Pl[w];

  auto STAGE_K = [&](int buf, int kt) {
    #pragma unroll
    for (int p = 0; p < 2; ++p) {
      int gg = t + (p << 9);
      int rk = gg >> 4, ck = gg & 15, sk = ck ^ (rk & 15);
      const u16* ga = Kp + (size_t)((kt << 6) + rk) * 128 + (sk << 3);
      GLDS16(ga, (char*)Kl[buf] + gg * 16);
    }
  };
  auto STAGE_V = [&](int kt) {
    #pragma unroll
    for (int p = 0; p < 2; ++p) {
      int gg = t + (p << 9);
      int rv = gg >> 3, cv = gg & 7, sv = cv ^ (rv & 7);
      const u16* gv = Vp + (size_t)rv * S + (kt << 6) + (sv << 3);
      GLDS16(gv, (char*)Vl + gg * 16);
    }
  };

  const int ntiles = (qtg << 1) + 2;
  STAGE_K(0, 0);
  __syncthreads();

  for (int kt = 0; kt < ntiles; ++kt) {
    int kv0 = kt << 6;
    int ktn = (kt + 1 < ntiles) ? kt + 1 : kt;   // clamp: last iter re-stages idle buffer
    STAGE_V(kt);                                  // consumed after mid-iter barrier
    STAGE_K((kt + 1) & 1, ktn);                   // consumed next iteration

    bool part = (kv0 <= qw + 15);
    bf16x8 pf[2];
    if (part) {
      // ---- QK^T swapped from pre-staged K: sc[nt][r] = S[kv=kv0+nt*16+hi*4+r][q=qme] ----
      const char* Kcur = (const char*)Kl[kt & 1];
      f32x4 sc[4];
      __builtin_amdgcn_s_setprio(1);
      #pragma unroll
      for (int nt = 0; nt < 4; ++nt) {
        f32x4 a = (f32x4){0.f, 0.f, 0.f, 0.f};
        int row = (nt << 4) + r15;
        #pragma unroll
        for (int kk = 0; kk < 4; ++kk) {
          int ch = (kk << 2) + hi;
          bf16x8 kf = *(const bf16x8*)(Kcur + row * 256 + ((ch ^ (row & 15)) << 4));
          a = mfma16(kf, qf[kk], a);
        }
        sc[nt] = a;
      }
      __builtin_amdgcn_s_setprio(0);

      // ---- mask (diagonal tiles only) ----
      if (kv0 + 63 > qw) {
        #pragma unroll
        for (int nt = 0; nt < 4; ++nt) {
          int kvb = kv0 + (nt << 4) + (hi << 2);
          #pragma unroll
          for (int r = 0; r < 4; ++r)
            sc[nt][r] = (kvb + r <= qme) ? sc[nt][r] : -1e30f;
        }
      }

      // ---- online softmax: in-lane over 16 values + 2 hops ----
      f32x4 mx = sc[0];
      #pragma unroll
      for (int nt = 1; nt < 4; ++nt) {
        mx[0] = fmaxf(mx[0], sc[nt][0]); mx[1] = fmaxf(mx[1], sc[nt][1]);
        mx[2] = fmaxf(mx[2], sc[nt][2]); mx[3] = fmaxf(mx[3], sc[nt][3]);
      }
      float mt = fmaxf(fmaxf(mx[0], mx[1]), fmaxf(mx[2], mx[3]));
      mt = fmaxf(mt, __shfl_xor(mt, 16, 64));
      mt = fmaxf(mt, __shfl_xor(mt, 32, 64));
      float mn = fmaxf(mrun, mt);
      float cr = fexp2(mrun - mn);
      float ps = 0.f;
      #pragma unroll
      for (int nt = 0; nt < 4; ++nt) {
        #pragma unroll
        for (int r = 0; r < 4; ++r) {
          float pv = fexp2(sc[nt][r] - mn);
          sc[nt][r] = pv;
          ps += pv;
        }
      }
      ps += __shfl_xor(ps, 16, 64);
      ps += __shfl_xor(ps, 32, 64);
      lrun = lrun * cr + ps;
      mrun = mn;

      // ---- rescale O^T ----
      #pragma unroll
      for (int dt = 0; dt < 8; ++dt) {
        f32x4 t4 = o[dt];
        t4[0] *= cr; t4[1] *= cr; t4[2] *= cr; t4[3] *= cr;
        o[dt] = t4;
      }

      // ---- P^T -> per-wave LDS, then reread as B-fragment (per-wave private) ----
      #pragma unroll
      for (int nt = 0; nt < 4; ++nt) {
        ushort4 pk;
        pk.x = f2b(sc[nt][0]); pk.y = f2b(sc[nt][1]);
        pk.z = f2b(sc[nt][2]); pk.w = f2b(sc[nt][3]);
        int chunk = ((nt << 1) + (hi >> 1)) ^ (r15 & 7);
        *(ushort4*)((char*)pw + r15 * 128 + (chunk << 4) + ((hi & 1) << 3)) = pk;
      }
      #pragma unroll
      for (int m = 0; m < 2; ++m) {
        int chunk = ((m << 2) + hi) ^ (r15 & 7);
        pf[m] = *(const bf16x8*)((const char*)pw + r15 * 128 + (chunk << 4));
      }
    }

    __syncthreads();   // per-wave vmcnt(0) drain + rendezvous => Vl (and K next) ready

    if (part) {
      // ---- PV: o^T += V^T * P^T ----
      __builtin_amdgcn_s_setprio(1);
      #pragma unroll
      for (int dt = 0; dt < 8; ++dt) {
        int vrow = (dt << 4) + r15;
        #pragma unroll
        for (int m = 0; m < 2; ++m) {
          int chv = (m << 2) + hi;
          bf16x8 vf = *(const bf16x8*)((const char*)Vl + vrow * 128 + ((chv ^ (vrow & 7)) << 4));
          o[dt] = mfma16(vf, pf[m], o[dt]);
        }
      }
      __builtin_amdgcn_s_setprio(0);
    }

    __syncthreads();   // all PV reads of Vl done before next iter overwrites it
  }

  // epilogue: normalize, pack d-contiguous ushort4, store AO[b*S+q][h*128+d]
  float inv = 1.0f / lrun;
  size_t rowb = (size_t)(b * 2048 + qw + r15) * 2048 + h * 128 + (hi << 2);
  #pragma unroll
  for (int dt = 0; dt < 8; ++dt) {
    ushort4 ov;
    ov.x = f2b(o[dt][0] * inv); ov.y = f2b(o[dt][1] * inv);
    ov.z = f2b(o[dt][2] * inv); ov.w = f2b(o[dt][3] * inv);
    *(ushort4*)(AO + rowb + (dt << 4)) = ov;
  }
}

// ---------------- host ----------------
extern "C" void kernel_launch(void* const* d_in, const int* in_sizes, int n_in,
                              void* d_out, int out_size, void* d_ws, size_t ws_size,
                              hipStream_t stream)
{
  const float* x        = (const float*)d_in[0];
  const float* Wq_down  = (const float*)d_in[1];
  const float* Wq_up    = (const float*)d_in[2];
  const float* Wq_rope  = (const float*)d_in[3];
  const float* Wkv_down = (const float*)d_in[4];
  const float* Wk_up    = (const float*)d_in[5];
  const float* Wk_rope  = (const float*)d_in[6];
  const float* Wv_up    = (const float*)d_in[7];
  const float* Wo       = (const float*)d_in[8];

  char* ws = (char*)d_ws;
  u16* xb    = (u16*)(ws + 0);          // 16 MB; reused as AO after GEMM1
  u16* W1t   = (u16*)(ws + 16777216);   // [2560][2048]
  u16* W2t   = (u16*)(ws + 27262976);   // [2048][1024]
  u16* W3t   = (u16*)(ws + 31457280);   // [3072][512]
  u16* Wot   = (u16*)(ws + 34603008);   // [2048][2048]
  u16* lat1  = (u16*)(ws + 42991616);   // [4096][2560]  q_lat|kv_lat (cols 1536+ unused now)
  u16* Qb    = (u16*)(ws + 105906176);  // [32][2048][128]
  u16* Kb    = (u16*)(ws + 122683392);
  u16* Vtb   = (u16*)(ws + 139460608);  // [32][128][2048]
  u16* AO    = xb;
  if (ws_size < 156237824u) return;     // visible failure instead of OOB

  rope_fill<<<256, 256, 0, stream>>>();
  conv_f32_bf16<<<2048, 256, 0, stream>>>(x, xb, 2097152);

  wtrans<<<dim3(32, 64), 256, 0, stream>>>(Wq_down,  2048, 1024, W1t, 2048, 0);
  wtrans<<<dim3(16, 64), 256, 0, stream>>>(Wkv_down, 2048,  512, W1t, 2048, 1024);
  wtrans<<<dim3(32, 64), 256, 0, stream>>>(Wk_rope,  2048, 1024, W1t, 2048, 1536);
  wtrans<<<dim3(32, 32), 256, 0, stream>>>(Wq_up,    1024, 1024, W2t, 1024, 0);
  wtrans<<<dim3(32, 32), 256, 0, stream>>>(Wq_rope,  1024, 1024, W2t, 1024, 1024);
  wtrans<<<dim3(32, 16), 256, 0, stream>>>(Wk_up,     512, 1024, W3t,  512, 0);
  wtrans<<<dim3(64, 16), 256, 0, stream>>>(Wv_up,     512, 2048, W3t,  512, 1024);
  wtrans<<<dim3(64, 64), 256, 0, stream>>>(Wo,       2048, 2048, Wot, 2048, 0);

  // GEMM1: lat1 = xb @ [Wq_down|Wkv_down|Wk_rope]; k_pe rope-fused -> Kb[..][64:128]
  gemm_bt<<<dim3(20, 32), 256, 0, stream>>>(xb, W1t, lat1, 2048, 2048, 2048, 2560, 2, Kb, nullptr);
  // GEMM2: q = q_lat @ [Wq_up|Wq_rope]; fully fused -> Qb (nope + rope, scaled)
  gemm_bt<<<dim3(16, 32), 256, 0, stream>>>(lat1, W2t, Qb, 1024, 2560, 1024, 2048, 3, Qb, nullptr);
  // GEMM3: [k_nope|v] = kv_lat @ [Wk_up|Wv_up]; fused -> Kb[..][0:64] + Vt transposed
  gemm_bt<<<dim3(24, 32), 256, 0, stream>>>(lat1 + 1024, W3t, Kb, 512, 2560, 512, 3072, 4, Kb, Vtb);

  attn_fwd<<<512, 512, 0, stream>>>(Qb, Kb, Vtb, AO);

  // out = AO @ Wo  (f32 out)
  gemm_bt<<<dim3(16, 32), 256, 0, stream>>>(AO, Wot, d_out, 2048, 2048, 2048, 2048, 1, nullptr, nullptr);

  (void)in_sizes; (void)n_in; (void)out_size;
}